// Round 9
// baseline (27.511 us; speedup 1.0000x reference)
//
#include <hip/hip_runtime.h>

// GrowingSignature: truncated iterated-sums signature, levels 1..4, F=4.
// x: (32, 512, 4) f32;  out: (32, 512, 341) f32.
// 2-kernel chunked scan, CS=16 / C=32 (1024 blocks each -> 4 blocks/CU).
// sigC Chen-combines its prefix directly from global/L2 (no LDS staging,
// rows are read exactly once), then runs the plain running-signature
// recursion (4 FMA/step) seeded with that prefix.
// Word layout (signatory order): len1 cols 1..4, len2 cols 5..20,
// len3 cols 21..84, len4 cols 85..340; word (a,b,c,e) -> 85+64a+16b+4c+e.

#define SIG_B 32
#define SIG_L 512
#define SIG_NSTEP 511
#define SIG_ROW 341
#define SIG_CS 16            // chunk size (increments)
#define SIG_C 32             // chunks per batch
#define SIG_PAD 344          // workspace row stride (floats, %4==0)

// ---------- Kernel A: local chunk signatures ----------
__global__ __launch_bounds__(256) void sigA(const float* __restrict__ x,
                                            float* __restrict__ Lsig) {
    const int bc = blockIdx.x;
    const int b = bc / SIG_C, c = bc % SIG_C;
    const int tid = threadIdx.x;
    const int t0 = c * SIG_CS;
    const int nt = min(SIG_CS, SIG_NSTEP - t0);   // 16, or 15 for c=31

    __shared__ float dlds[SIG_CS * 4];
    const float* xb = x + ((size_t)b * SIG_L + t0) * 4;
    if (tid < SIG_CS) {
        float4 d = make_float4(0.f, 0.f, 0.f, 0.f);
        if (tid < nt) {
            float4 x0 = *(const float4*)(xb + tid * 4);
            float4 x1 = *(const float4*)(xb + (tid + 1) * 4);
            d = make_float4(x1.x - x0.x, x1.y - x0.y, x1.z - x0.z, x1.w - x0.w);
        }
        *(float4*)(dlds + tid * 4) = d;           // zero-padded tail
    }
    __syncthreads();

    const int a = tid >> 6, bb = (tid >> 4) & 3, cc = (tid >> 2) & 3, ee = tid & 3;
    float s1 = 0.f, s2 = 0.f, s3 = 0.f, s4 = 0.f;
#pragma unroll
    for (int t = 0; t < SIG_CS; ++t) {            // constant trip -> full unroll
        const float* dp = dlds + t * 4;
        const float da = dp[a], db = dp[bb], dc = dp[cc], de = dp[ee];
        s4 = fmaf(s3, de, s4);  // top level first: consumes pre-update s3
        s3 = fmaf(s2, dc, s3);
        s2 = fmaf(s1, db, s2);
        s1 += da;
    }
    float* Lr = Lsig + (size_t)bc * SIG_PAD;
    if ((tid & 63) == 0) Lr[1 + a] = s1;
    if ((tid & 15) == 0) Lr[5 + (tid >> 4)] = s2;
    if ((tid & 3) == 0)  Lr[21 + (tid >> 2)] = s3;
    Lr[85 + tid] = s4;
}

// ---------- Kernel C: direct-L2 prefix combine + running-signature scan ----------
__global__ __launch_bounds__(256) void sigC(const float* __restrict__ x,
                                            const float* __restrict__ Lsig,
                                            float* __restrict__ out) {
    const int bc = blockIdx.x;
    const int b = bc / SIG_C, c = bc % SIG_C;
    const int tid = threadIdx.x;
    const int t0 = c * SIG_CS;
    const int nt = min(SIG_CS, SIG_NSTEP - t0);

    __shared__ float dlds[SIG_CS * 4];
    const float* xb = x + ((size_t)b * SIG_L + t0) * 4;
    if (tid < SIG_CS) {
        float4 d = make_float4(0.f, 0.f, 0.f, 0.f);
        if (tid < nt) {
            float4 x0 = *(const float4*)(xb + tid * 4);
            float4 x1 = *(const float4*)(xb + (tid + 1) * 4);
            d = make_float4(x1.x - x0.x, x1.y - x0.y, x1.z - x0.z, x1.w - x0.w);
        }
        *(float4*)(dlds + tid * 4) = d;           // zero-padded tail
    }
    __syncthreads();

    const int a = tid >> 6, bb = (tid >> 4) & 3, cc = (tid >> 2) & 3, ee = tid & 3;

    // Chen-combine chunks 0..c-1 straight from global (L2-resident; each row
    // is consumed exactly once, so LDS staging would be pure overhead).
    float p1 = 0.f, p2 = 0.f, p3 = 0.f, p4 = 0.f;
    const float* Lb = Lsig + (size_t)b * SIG_C * SIG_PAD;
#pragma unroll 4
    for (int j = 0; j < c; ++j) {
        const float* Lc = Lb + (size_t)j * SIG_PAD;
        const float l1a = Lc[1 + a], l1b = Lc[1 + bb], l1c = Lc[1 + cc], l1e = Lc[1 + ee];
        const float l2ab = Lc[5 + 4 * a + bb], l2bc = Lc[5 + 4 * bb + cc],
                    l2ce = Lc[5 + 4 * cc + ee];
        const float l3abc = Lc[21 + 16 * a + 4 * bb + cc],
                    l3bce = Lc[21 + 16 * bb + 4 * cc + ee];
        const float l4 = Lc[85 + tid];
        p4 += p3 * l1e + p2 * l2ce + p1 * l3bce + l4;  // uses pre-update p1..p3
        p3 += p2 * l1c + p1 * l2bc + l3abc;
        p2 += p1 * l1b + l2ab;
        p1 += l1a;
    }

    float* row = out + ((size_t)b * SIG_L + (t0 + 1)) * SIG_ROW;

    if (c == 0) {  // row 0: [1, zeros]
        float* r0 = out + (size_t)b * SIG_L * SIG_ROW;
        if (tid == 0)        __builtin_nontemporal_store(1.0f, r0 + 0);
        if ((tid & 63) == 0) __builtin_nontemporal_store(0.f, r0 + 1 + a);
        if ((tid & 15) == 0) __builtin_nontemporal_store(0.f, r0 + 5 + (tid >> 4));
        if ((tid & 3) == 0)  __builtin_nontemporal_store(0.f, r0 + 21 + (tid >> 2));
        __builtin_nontemporal_store(0.f, r0 + 85 + tid);
    }

    // Plain running-signature recursion seeded with the prefix: 4 FMA/step.
#pragma unroll
    for (int t = 0; t < SIG_CS; ++t) {            // constant trip -> full unroll
        const float* dp = dlds + t * 4;
        const float da = dp[a], db = dp[bb], dc = dp[cc], de = dp[ee];
        p4 = fmaf(p3, de, p4);  // top level first: consumes pre-update p3
        p3 = fmaf(p2, dc, p3);
        p2 = fmaf(p1, db, p2);
        p1 += da;

        if (t < nt) {  // uniform guard (only c=31 pads one step)
            float* r = row + (size_t)t * SIG_ROW;
            if (tid == 0)        __builtin_nontemporal_store(1.0f, r + 0);
            if ((tid & 63) == 0) __builtin_nontemporal_store(p1, r + 1 + a);
            if ((tid & 15) == 0) __builtin_nontemporal_store(p2, r + 5 + (tid >> 4));
            if ((tid & 3) == 0)  __builtin_nontemporal_store(p3, r + 21 + (tid >> 2));
            __builtin_nontemporal_store(p4, r + 85 + tid);  // coalesced
        }
    }
}

extern "C" void kernel_launch(void* const* d_in, const int* in_sizes, int n_in,
                              void* d_out, int out_size, void* d_ws, size_t ws_size,
                              hipStream_t stream) {
    const float* x = (const float*)d_in[0];   // (32, 512, 4) f32
    float* out = (float*)d_out;               // (32, 512, 341) f32
    float* Lsig = (float*)d_ws;               // 1024 * 344 floats (~1.4 MB)

    sigA<<<SIG_B * SIG_C, 256, 0, stream>>>(x, Lsig);
    sigC<<<SIG_B * SIG_C, 256, 0, stream>>>(x, Lsig, out);
}

// Round 10
// 21.912 us; speedup vs baseline: 1.2555x; 1.2555x over previous
//
#include <hip/hip_runtime.h>

// GrowingSignature: truncated iterated-sums signature, levels 1..4, F=4.
// x: (32, 512, 4) f32;  out: (32, 512, 341) f32.
// 2-kernel chunked scan (CS=32, C=16) — R8 structure. The output scan is the
// plain running-signature recursion seeded with the Chen-combined chunk
// prefix (a single-step Chen product only touches level 1 -> 4 FMA/step).
// R10 change vs R8: plain stores instead of nontemporal — output (22.3 MB)
// fits L2 (32 MB); regular stores complete at L2 and drain after kernel end,
// NT stores put the HBM write path on the kernel's critical path.
// Word layout (signatory order): len1 cols 1..4, len2 cols 5..20,
// len3 cols 21..84, len4 cols 85..340; word (a,b,c,e) -> 85+64a+16b+4c+e.

#define SIG_B 32
#define SIG_L 512
#define SIG_NSTEP 511
#define SIG_ROW 341
#define SIG_CS 32            // chunk size (increments)
#define SIG_C 16             // chunks per batch
#define SIG_PAD 344          // padded row stride in workspace (floats, %4==0)

// ---------- Kernel A: local chunk signatures ----------
__global__ __launch_bounds__(256) void sigA(const float* __restrict__ x,
                                            float* __restrict__ Lsig) {
    const int bc = blockIdx.x;
    const int b = bc / SIG_C, c = bc % SIG_C;
    const int tid = threadIdx.x;
    const int t0 = c * SIG_CS;
    const int nt = min(SIG_CS, SIG_NSTEP - t0);   // 32, or 31 for last chunk

    __shared__ float dlds[SIG_CS * 4];
    const float* xb = x + ((size_t)b * SIG_L + t0) * 4;
    if (tid < nt) {
        float4 x0 = *(const float4*)(xb + tid * 4);
        float4 x1 = *(const float4*)(xb + (tid + 1) * 4);
        *(float4*)(dlds + tid * 4) =
            make_float4(x1.x - x0.x, x1.y - x0.y, x1.z - x0.z, x1.w - x0.w);
    }
    __syncthreads();

    const int a = tid >> 6, bb = (tid >> 4) & 3, cc = (tid >> 2) & 3, ee = tid & 3;
    float s1 = 0.f, s2 = 0.f, s3 = 0.f, s4 = 0.f;
    const float* dp = dlds;
    for (int t = 0; t < nt; ++t) {
        const float da = dp[a], db = dp[bb], dc = dp[cc], de = dp[ee];
        dp += 4;
        s4 = fmaf(s3, de, s4);  // top level first: consumes pre-update s3
        s3 = fmaf(s2, dc, s3);
        s2 = fmaf(s1, db, s2);
        s1 += da;
    }
    float* Lr = Lsig + (size_t)bc * SIG_PAD;
    if ((tid & 63) == 0) Lr[1 + a] = s1;
    if ((tid & 15) == 0) Lr[5 + (tid >> 4)] = s2;
    if ((tid & 3) == 0)  Lr[21 + (tid >> 2)] = s3;
    Lr[85 + tid] = s4;
}

// ---------- Kernel C: prefix combine + plain running-signature scan ----------
__global__ __launch_bounds__(256) void sigC(const float* __restrict__ x,
                                            const float* __restrict__ Lsig,
                                            float* __restrict__ out) {
    const int bc = blockIdx.x;
    const int b = bc / SIG_C, c = bc % SIG_C;
    const int tid = threadIdx.x;
    const int t0 = c * SIG_CS;
    const int nt = min(SIG_CS, SIG_NSTEP - t0);

    __shared__ float dlds[SIG_CS * 4];
    __shared__ float L[SIG_C * SIG_PAD];

    const float* xb = x + ((size_t)b * SIG_L + t0) * 4;
    if (tid < nt) {
        float4 x0 = *(const float4*)(xb + tid * 4);
        float4 x1 = *(const float4*)(xb + (tid + 1) * 4);
        *(float4*)(dlds + tid * 4) =
            make_float4(x1.x - x0.x, x1.y - x0.y, x1.z - x0.z, x1.w - x0.w);
    }
    // Stage the c preceding chunk signatures (only what this block combines).
    {
        const float4* Lb4 = (const float4*)(Lsig + (size_t)b * SIG_C * SIG_PAD);
        float4* L4p = (float4*)L;
        const int n4 = c * (SIG_PAD / 4);
        for (int i = tid; i < n4; i += 256) L4p[i] = Lb4[i];
    }
    __syncthreads();

    const int a = tid >> 6, bb = (tid >> 4) & 3, cc = (tid >> 2) & 3, ee = tid & 3;

    // Chen-combine chunks 0..c-1 -> prefix (p1..p4) for this lane's word.
    float p1 = 0.f, p2 = 0.f, p3 = 0.f, p4 = 0.f;
    for (int j = 0; j < c; ++j) {
        const float* Lc = L + j * SIG_PAD;
        const float l1a = Lc[1 + a], l1b = Lc[1 + bb], l1c = Lc[1 + cc], l1e = Lc[1 + ee];
        const float l2ab = Lc[5 + 4 * a + bb], l2bc = Lc[5 + 4 * bb + cc],
                    l2ce = Lc[5 + 4 * cc + ee];
        const float l3abc = Lc[21 + 16 * a + 4 * bb + cc],
                    l3bce = Lc[21 + 16 * bb + 4 * cc + ee];
        const float l4 = Lc[85 + tid];
        p4 += p3 * l1e + p2 * l2ce + p1 * l3bce + l4;  // uses pre-update p1..p3
        p3 += p2 * l1c + p1 * l2bc + l3abc;
        p2 += p1 * l1b + l2ab;
        p1 += l1a;
    }

    float* row = out + ((size_t)b * SIG_L + (t0 + 1)) * SIG_ROW;

    if (c == 0) {  // row 0: [1, zeros]
        float* r0 = out + (size_t)b * SIG_L * SIG_ROW;
        if (tid == 0)        r0[0] = 1.0f;
        if ((tid & 63) == 0) r0[1 + a] = 0.f;
        if ((tid & 15) == 0) r0[5 + (tid >> 4)] = 0.f;
        if ((tid & 3) == 0)  r0[21 + (tid >> 2)] = 0.f;
        r0[85 + tid] = 0.f;
    }

    // Plain running-signature recursion seeded with the prefix: 4 FMA/step.
    const float* dp = dlds;
    for (int t = 0; t < nt; ++t) {
        const float da = dp[a], db = dp[bb], dc = dp[cc], de = dp[ee];
        dp += 4;
        p4 = fmaf(p3, de, p4);  // top level first: consumes pre-update p3
        p3 = fmaf(p2, dc, p3);
        p2 = fmaf(p1, db, p2);
        p1 += da;

        if (tid == 0)        row[0] = 1.0f;
        if ((tid & 63) == 0) row[1 + a] = p1;
        if ((tid & 15) == 0) row[5 + (tid >> 4)] = p2;
        if ((tid & 3) == 0)  row[21 + (tid >> 2)] = p3;
        row[85 + tid] = p4;   // coalesced: consecutive lanes, consecutive dwords
        row += SIG_ROW;
    }
}

extern "C" void kernel_launch(void* const* d_in, const int* in_sizes, int n_in,
                              void* d_out, int out_size, void* d_ws, size_t ws_size,
                              hipStream_t stream) {
    const float* x = (const float*)d_in[0];   // (32, 512, 4) f32
    float* out = (float*)d_out;               // (32, 512, 341) f32
    float* Lsig = (float*)d_ws;               // 512 * 344 floats

    sigA<<<SIG_B * SIG_C, 256, 0, stream>>>(x, Lsig);
    sigC<<<SIG_B * SIG_C, 256, 0, stream>>>(x, Lsig, out);
}